// Round 21
// baseline (254.490 us; speedup 1.0000x reference)
//
#include <hip/hip_runtime.h>
#include <hip/hip_bf16.h>

typedef __attribute__((ext_vector_type(8))) short bf16x8;
typedef __attribute__((ext_vector_type(4))) float f32x4;

// LDS (82 KB, one 512-thread block/CU):
//   LXW shared read-only XW; per-group LT (T, att overlays own rows) and LV;
//   LRW rank-1 terms; epilogue exchange overlays LT0+LT1.
#define LXW  0
#define LTB  16384   // group g: LT = LTB + g*16384
#define LVB  49152   // group g: LV = LVB + g*16384
#define LRW  81920
#define LEX  16384   // epilogue exchange region (64 rows x 512B)

__device__ __forceinline__ int sw256(int o){ return o ^ (((o >> 8) & 7) << 4); }
__device__ __forceinline__ int sw128(int o){ return o ^ (((o >> 7) & 7) << 4); }

// native f32->bf16 RNE conversion
__device__ __forceinline__ short f2bf(float f){
  union { __hip_bfloat16 h; short s; } u;
  u.h = __float2bfloat16(f);
  return u.s;
}
__device__ __forceinline__ float bf2f(short s){
  union { unsigned u; float f; } v; v.u = ((unsigned)(unsigned short)s) << 16;
  return v.f;
}
__device__ __forceinline__ bf16x8 lds8(const char* smem, int off){
  return *(const bf16x8*)(smem + off);
}

// Wfused_h = pw_h . wv_h  (bf16), bfused_h[co] = sum_d wv_b[h*128+d]*pw[co][h*128+d]
__global__ void wfused_k(const float* __restrict__ pw, const float* __restrict__ wv,
                         const float* __restrict__ wv_b,
                         short* __restrict__ wf, float* __restrict__ bf) {
  int blk = blockIdx.x;             // h*128 + co
  int h = blk >> 7, co = blk & 127;
  int ci = threadIdx.x;             // 0..127
  const float* pr = pw + (size_t)co * 1024 + h * 128;   // pw[co][h*128+d]
  const float* wr = wv + (size_t)h * 128 * 128 + ci;    // wv[h*128+d][ci]
  float acc = 0.f;
#pragma unroll 4
  for (int d = 0; d < 128; ++d)
    acc += pr[d] * wr[(size_t)d * 128];
  wf[(size_t)h * 16384 + co * 128 + ci] = f2bf(acc);
  if (ci < 64) {
    float b = wv_b[h*128 + ci] * pr[ci] + wv_b[h*128 + 64 + ci] * pr[64 + ci];
    b += __shfl_xor(b, 1);  b += __shfl_xor(b, 2);  b += __shfl_xor(b, 4);
    b += __shfl_xor(b, 8);  b += __shfl_xor(b, 16); b += __shfl_xor(b, 32);
    if (ci == 0) bf[h*128 + co] = b;
  }
}

// Mt[h][kp][k] = isdk * sum_d Wk[d][kp]*Wq[d][k]; u,v,c likewise pre-scaled.
__global__ void mt_k(const float* __restrict__ wq, const float* __restrict__ wk,
                     const float* __restrict__ bq, const float* __restrict__ bk,
                     short* __restrict__ mt, float* __restrict__ uarr,
                     float* __restrict__ varr, float* __restrict__ carr) {
  const float isdk = 0.088388347648318447f;  // 1/sqrt(128)
  int blk = blockIdx.x;             // h*128 + kp
  int h = blk >> 7, kp = blk & 127;
  int ci = threadIdx.x;             // 0..127 = k
  const float* wkc = wk + (size_t)h * 16384 + kp;   // Wk[d][kp], stride 128
  const float* wqc = wq + (size_t)h * 16384 + ci;   // Wq[d][k],  stride 128
  float macc = 0.f, vacc = 0.f;
#pragma unroll 4
  for (int d = 0; d < 128; ++d) {
    float wqv = wqc[(size_t)d * 128];
    macc += wkc[(size_t)d * 128] * wqv;
    vacc += bk[h*128 + d] * wqv;
  }
  mt[(size_t)h * 16384 + kp * 128 + ci] = f2bf(macc * isdk);
  if (ci == 0) {
    float u = 0.f;
#pragma unroll 4
    for (int d = 0; d < 128; ++d) u += bq[h*128 + d] * wkc[(size_t)d * 128];
    uarr[h*128 + kp] = u * isdk;
  }
  if (kp == 0) {
    varr[h*128 + ci] = vacc * isdk;
    if (ci == 0) {
      float c = 0.f;
#pragma unroll 4
      for (int d = 0; d < 128; ++d) c += bq[h*128 + d] * bk[h*128 + d];
      carr[h] = c * isdk;
    }
  }
}

__global__ __launch_bounds__(512, 1) void swattn_main(
    const float* __restrict__ x, const float* __restrict__ mask,
    const float* __restrict__ Bp, const float* __restrict__ proj_b,
    const short* __restrict__ mt, const short* __restrict__ wfz,
    const float* __restrict__ uarr, const float* __restrict__ bfu,
    const float* __restrict__ varr, const float* __restrict__ carr,
    float* __restrict__ out)
{
  __shared__ alignas(16) char smem[83968];
  const int tid  = threadIdx.x;
  const int wvid = tid >> 6, lane = tid & 63, lr = lane & 15, lg = lane >> 4;
  const int g    = wvid >> 2;         // head-parity group (0: even, 1: odd)
  const int wq4  = wvid & 3;          // wave within group
  const int rbp  = (wq4 >> 1) * 2;    // phase-1 row-block pair
  const int jh   = wq4 & 1;           // phase-1 j half
  const int LT   = LTB + g*16384;
  const int LV   = LVB + g*16384;
  const int wid = blockIdx.x;
  const int bb = wid >> 8, wy = (wid >> 4) & 15, wx = wid & 15;

  // ---- gather shifted window into LDS (LXW, shared read-only) as bf16 ----
  {
    int token = tid >> 3, q = tid & 7;   // 8 threads/token, 16 floats each
    int py = token >> 3, px = token & 7;
    int Y = (wy*8 + py + 4) & 127;
    int X = (wx*8 + px + 4) & 127;
    int swin = bb*256 + ((Y>>3)<<4) + (X>>3);
    int stok = ((Y&7)<<3) + (X&7);
    const float* src = x + ((size_t)(swin*64 + stok))*128 + q*16;
    int base = LXW + token*256 + q*32;
#pragma unroll
    for (int j = 0; j < 16; j += 8) {
      float4 f0 = *(const float4*)(src + j);
      float4 f1 = *(const float4*)(src + j + 4);
      bf16x8 bv;
      bv[0]=f2bf(f0.x); bv[1]=f2bf(f0.y); bv[2]=f2bf(f0.z); bv[3]=f2bf(f0.w);
      bv[4]=f2bf(f1.x); bv[5]=f2bf(f1.y); bv[6]=f2bf(f1.z); bv[7]=f2bf(f1.w);
      *(bf16x8*)(smem + sw256(base + j*2)) = bv;
    }
  }
  __syncthreads();

  // ---- hoist this wave's 2 row-blocks of XW A-fragments (32 VGPR) ----
  bf16x8 af[2][4];
#pragma unroll
  for (int r2 = 0; r2 < 2; ++r2) {
    int arow = (rbp + r2)*16 + lr;
#pragma unroll
    for (int kk = 0; kk < 4; ++kk)
      af[r2][kk] = *(const bf16x8*)(smem + sw256(LXW + arow*256 + kk*64 + lg*16));
  }

  // ---- rw8[h][i] = v_h . xw_i + c_h  (once per window; pre-scaled) ----
  {
    int e = tid;                      // 512 threads -> all 8h x 64i
    int h = e >> 6, i = e & 63;
    float acc = carr[h];
#pragma unroll
    for (int k8 = 0; k8 < 16; ++k8) {
      bf16x8 xv = lds8(smem, sw256(LXW + i*256 + k8*16));
      float4 va = *(const float4*)(varr + h*128 + k8*8);
      float4 vb = *(const float4*)(varr + h*128 + k8*8 + 4);
      acc += bf2f(xv[0])*va.x + bf2f(xv[1])*va.y + bf2f(xv[2])*va.z + bf2f(xv[3])*va.w;
      acc += bf2f(xv[4])*vb.x + bf2f(xv[5])*vb.y + bf2f(xv[6])*vb.z + bf2f(xv[7])*vb.w;
    }
    *(float*)(smem + LRW + e*4) = acc;
  }
  __syncthreads();   // rw8 visible; LXW reads below are read-only

  // ---- border-mask pointer only ----
  const float* mrow = nullptr;
  if (wy == 15 && wx != 15)      mrow = mask;
  else if (wx == 15 && wy != 15) mrow = mask + 4096;
  else if (wy == 15 && wx == 15) mrow = mask + 8192;

  f32x4 accO[8];
#pragma unroll
  for (int ct = 0; ct < 8; ++ct) accO[ct] = f32x4{0.f, 0.f, 0.f, 0.f};

  for (int it = 0; it < 4; ++it) {
    const int h = 2*it + g;          // group 0: even heads, group 1: odd heads

    // ===== Phase 1: T = XW.Mt^T (+u) and Vp = XW.Wfz^T (+bfu) ====
    // Per s-matrix: ALL 16 fragment loads + 4 biases in flight (256-reg cap).
#pragma unroll
    for (int s = 0; s < 2; ++s) {
      const short* wbase = s ? wfz : mt;
      const float* bbase = s ? bfu : uarr;
      bf16x8 bfvA[4][4];
      float biasA[4];
#pragma unroll
      for (int t = 0; t < 4; ++t) {
        int j = (jh*4 + t)*16 + lr;
        const short* wr = wbase + (size_t)(h*128 + j)*128;
#pragma unroll
        for (int kk = 0; kk < 4; ++kk)
          bfvA[t][kk] = *(const bf16x8*)(wr + kk*32 + lg*8);
        biasA[t] = bbase[h*128 + j];
      }
#pragma unroll
      for (int t = 0; t < 4; ++t) {
        int j = (jh*4 + t)*16 + lr;
        float bias = biasA[t];
#pragma unroll
        for (int r2 = 0; r2 < 2; ++r2) {
          int rb = rbp + r2;
          f32x4 acc = f32x4{0.f,0.f,0.f,0.f};
#pragma unroll
          for (int kk = 0; kk < 4; ++kk)
            acc = __builtin_amdgcn_mfma_f32_16x16x32_bf16(af[r2][kk], bfvA[t][kk], acc, 0,0,0);
          if (s == 0) {  // T row-major [token][kp], pitch 256B
#pragma unroll
            for (int rr = 0; rr < 4; ++rr) {
              int row = rb*16 + lg*4 + rr;
              *(short*)(smem + sw256(LT + row*256 + j*2)) = f2bf(acc[rr] + bias);
            }
          } else {       // VpT[j][m], pitch 128B, pack 4 m's
            short4 p;
            p.x = f2bf(acc[0] + bias); p.y = f2bf(acc[1] + bias);
            p.z = f2bf(acc[2] + bias); p.w = f2bf(acc[3] + bias);
            int m0 = rb*16 + lg*4;
            *(short4*)(smem + sw128(LV + j*128 + m0*2)) = p;
          }
        }
      }
    }
    __syncthreads();   // bar 1: T/Vp complete (both groups)

    // ===== Phase 2: att = softmax(T.XW^T + rw + Bp) * wmask  (no max-sub) ====
    {
      float pv[4][4];  // [cb][rr]
      bf16x8 qf[4];
      int qrow = 16*wq4 + lr;
#pragma unroll
      for (int kk = 0; kk < 4; ++kk)
        qf[kk] = *(const bf16x8*)(smem + sw256(LT + qrow*256 + kk*64 + lg*16));
      int i0 = 16*wq4 + lg*4;
      float rwb[4];
#pragma unroll
      for (int rr = 0; rr < 4; ++rr)
        rwb[rr] = *(const float*)(smem + LRW + (h*64 + i0 + rr)*4);
      __builtin_amdgcn_s_setprio(1);
#pragma unroll
      for (int cb = 0; cb < 4; ++cb) {
        f32x4 at = f32x4{0.f,0.f,0.f,0.f};
        int krow = cb*16 + lr;
#pragma unroll
        for (int kk = 0; kk < 4; ++kk) {
          bf16x8 kf = *(const bf16x8*)(smem + sw256(LXW + krow*256 + kk*64 + lg*16));
          at = __builtin_amdgcn_mfma_f32_16x16x32_bf16(qf[kk], kf, at, 0,0,0);
        }
#pragma unroll
        for (int rr = 0; rr < 4; ++rr)
          pv[cb][rr] = at[rr] + rwb[rr] + Bp[(i0+rr)*64 + cb*16 + lr];
      }
      __builtin_amdgcn_s_setprio(0);
      // scores ~ N(0,1): exp is overflow-safe without max subtraction
#pragma unroll
      for (int rr = 0; rr < 4; ++rr) {
        float s = 0.f;
#pragma unroll
        for (int cb = 0; cb < 4; ++cb) { pv[cb][rr] = __expf(pv[cb][rr]); s += pv[cb][rr]; }
        s += __shfl_xor(s, 1); s += __shfl_xor(s, 2);
        s += __shfl_xor(s, 4); s += __shfl_xor(s, 8);
        float inv = 1.0f / s;
#pragma unroll
        for (int cb = 0; cb < 4; ++cb) pv[cb][rr] *= inv;
      }
      if (mrow) {
#pragma unroll
        for (int cb = 0; cb < 4; ++cb)
#pragma unroll
          for (int rr = 0; rr < 4; ++rr)
            pv[cb][rr] *= mrow[(i0+rr)*64 + cb*16 + lr];
      }
      // att overlays the wave's OWN LT rows (in-wave DS ordering; certified)
#pragma unroll
      for (int cb = 0; cb < 4; ++cb) {
        int mcol = cb*16 + lr;
#pragma unroll
        for (int rr = 0; rr < 4; ++rr)
          *(short*)(smem + sw256(LT + (i0+rr)*256 + mcol*2)) = f2bf(pv[cb][rr]);
      }
    }

    // ===== Phase 3: accO[q-slice][all 128 c] += att @ Vp ====
    {
      bf16x8 paf[2];
#pragma unroll
      for (int kk = 0; kk < 2; ++kk)
        paf[kk] = lds8(smem, sw256(LT + (16*wq4 + lr)*256 + kk*64 + lg*16));
      __builtin_amdgcn_s_setprio(1);
#pragma unroll
      for (int ct = 0; ct < 8; ++ct) {
        int d = ct*16 + lr;
#pragma unroll
        for (int kk = 0; kk < 2; ++kk) {
          bf16x8 vf = lds8(smem, sw128(LV + d*128 + kk*64 + lg*16));
          accO[ct] = __builtin_amdgcn_mfma_f32_16x16x32_bf16(paf[kk], vf, accO[ct], 0,0,0);
        }
      }
      __builtin_amdgcn_s_setprio(0);
    }
    __syncthreads();   // bar 2: LT/LV reads done before next iteration's P1
  }

  // ---- epilogue: sum the two head-parity groups, + proj_b, scatter ----
  if (g == 1) {
#pragma unroll
    for (int rr = 0; rr < 4; ++rr) {
      int i = 16*wq4 + lg*4 + rr;
#pragma unroll
      for (int ct = 0; ct < 8; ++ct)
        *(float*)(smem + LEX + i*512 + (ct*16 + lr)*4) = accO[ct][rr];
    }
  }
  __syncthreads();
  if (g == 0) {
#pragma unroll
    for (int rr = 0; rr < 4; ++rr) {
      int i = 16*wq4 + lg*4 + rr;
      int py = i >> 3, px = i & 7;
      int Y = (wy*8 + py + 4) & 127;
      int X = (wx*8 + px + 4) & 127;
      int dwin = bb*256 + ((Y>>3)<<4) + (X>>3);
      int dtok = ((Y&7)<<3) + (X&7);
      float* dst = out + ((size_t)(dwin*64 + dtok))*128;
#pragma unroll
      for (int ct = 0; ct < 8; ++ct) {
        int c = ct*16 + lr;
        float other = *(const float*)(smem + LEX + i*512 + c*4);
        dst[c] = accO[ct][rr] + other + proj_b[c];
      }
    }
  }
}

extern "C" void kernel_launch(void* const* d_in, const int* in_sizes, int n_in,
                              void* d_out, int out_size, void* d_ws, size_t ws_size,
                              hipStream_t stream) {
  (void)in_sizes; (void)n_in; (void)out_size; (void)ws_size;
  const float* x      = (const float*)d_in[0];
  const float* mask   = (const float*)d_in[1];
  const float* Bp     = (const float*)d_in[2];
  const float* wq_w   = (const float*)d_in[3];
  const float* wq_b   = (const float*)d_in[4];
  const float* wk_w   = (const float*)d_in[5];
  const float* wk_b   = (const float*)d_in[6];
  const float* wv_w   = (const float*)d_in[7];
  const float* wv_b   = (const float*)d_in[8];
  const float* proj_w = (const float*)d_in[9];
  const float* proj_b = (const float*)d_in[10];
  float* out = (float*)d_out;
  short* wsb  = (short*)d_ws;
  short* wfz  = wsb;                       // 131072 shorts
  short* mt   = wsb + 131072;              // 131072 shorts
  float* bfu  = (float*)(wsb + 262144);    // 1024 f
  float* uarr = bfu + 1024;                // 1024 f
  float* varr = bfu + 2048;                // 1024 f
  float* carr = bfu + 3072;                // 8 f

  wfused_k<<<1024, 128, 0, stream>>>(proj_w, wv_w, wv_b, wfz, bfu);
  mt_k<<<1024, 128, 0, stream>>>(wq_w, wk_w, wq_b, wk_b, mt, uarr, varr, carr);
  swattn_main<<<1024, 512, 0, stream>>>(x, mask, Bp, proj_b,
      mt, wfz, uarr, bfu, varr, carr, out);
}

// Round 22
// 173.660 us; speedup vs baseline: 1.4654x; 1.4654x over previous
//
#include <hip/hip_runtime.h>
#include <hip/hip_bf16.h>

typedef __attribute__((ext_vector_type(8))) short bf16x8;
typedef __attribute__((ext_vector_type(4))) float f32x4;

// LDS layout (50 KB): LXW persistent; LT/LV rebuilt per head;
// att overlays the wave's own LT rows (in-wave ordering, certified r15/r17);
// LRW rank-1 row terms.
#define LXW  0
#define LT   16384
#define LV   32768
#define LRW  49152

__device__ __forceinline__ int sw256(int o){ return o ^ (((o >> 8) & 7) << 4); }
__device__ __forceinline__ int sw128(int o){ return o ^ (((o >> 7) & 7) << 4); }

// native f32->bf16 RNE conversion
__device__ __forceinline__ short f2bf(float f){
  union { __hip_bfloat16 h; short s; } u;
  u.h = __float2bfloat16(f);
  return u.s;
}
__device__ __forceinline__ float bf2f(short s){
  union { unsigned u; float f; } v; v.u = ((unsigned)(unsigned short)s) << 16;
  return v.f;
}
__device__ __forceinline__ bf16x8 lds8(const char* smem, int off){
  return *(const bf16x8*)(smem + off);
}

// Merged setup: blk<1024 -> Wfused role; blk>=1024 -> Mt role (concurrent).
// Wfused_h = pw_h . wv_h (bf16); bfused_h[co] = sum_d wv_b[h*128+d]*pw[co][h*128+d]
// Mt[h][kp][k] = isdk * sum_d Wk[d][kp]*Wq[d][k]; u,v,c likewise pre-scaled.
__global__ void setup_k(const float* __restrict__ pw, const float* __restrict__ wv,
                        const float* __restrict__ wv_b,
                        const float* __restrict__ wq, const float* __restrict__ wk,
                        const float* __restrict__ bq, const float* __restrict__ bk,
                        short* __restrict__ wf, float* __restrict__ bf,
                        short* __restrict__ mt, float* __restrict__ uarr,
                        float* __restrict__ varr, float* __restrict__ carr) {
  const float isdk = 0.088388347648318447f;  // 1/sqrt(128)
  int blk = blockIdx.x;
  int ci = threadIdx.x;             // 0..127
  if (blk < 1024) {
    int h = blk >> 7, co = blk & 127;
    const float* pr = pw + (size_t)co * 1024 + h * 128;   // pw[co][h*128+d]
    const float* wr = wv + (size_t)h * 128 * 128 + ci;    // wv[h*128+d][ci]
    float acc = 0.f;
#pragma unroll 4
    for (int d = 0; d < 128; ++d)
      acc += pr[d] * wr[(size_t)d * 128];
    wf[(size_t)h * 16384 + co * 128 + ci] = f2bf(acc);
    if (ci < 64) {
      float b = wv_b[h*128 + ci] * pr[ci] + wv_b[h*128 + 64 + ci] * pr[64 + ci];
      b += __shfl_xor(b, 1);  b += __shfl_xor(b, 2);  b += __shfl_xor(b, 4);
      b += __shfl_xor(b, 8);  b += __shfl_xor(b, 16); b += __shfl_xor(b, 32);
      if (ci == 0) bf[h*128 + co] = b;
    }
  } else {
    blk -= 1024;
    int h = blk >> 7, kp = blk & 127;
    const float* wkc = wk + (size_t)h * 16384 + kp;   // Wk[d][kp], stride 128
    const float* wqc = wq + (size_t)h * 16384 + ci;   // Wq[d][k],  stride 128
    float macc = 0.f, vacc = 0.f;
#pragma unroll 4
    for (int d = 0; d < 128; ++d) {
      float wqv = wqc[(size_t)d * 128];
      macc += wkc[(size_t)d * 128] * wqv;
      vacc += bk[h*128 + d] * wqv;
    }
    mt[(size_t)h * 16384 + kp * 128 + ci] = f2bf(macc * isdk);
    if (ci == 0) {
      float u = 0.f;
#pragma unroll 4
      for (int d = 0; d < 128; ++d) u += bq[h*128 + d] * wkc[(size_t)d * 128];
      uarr[h*128 + kp] = u * isdk;
    }
    if (kp == 0) {
      varr[h*128 + ci] = vacc * isdk;
      if (ci == 0) {
        float c = 0.f;
#pragma unroll 4
        for (int d = 0; d < 128; ++d) c += bq[h*128 + d] * bk[h*128 + d];
        carr[h] = c * isdk;
      }
    }
  }
}

__global__ __launch_bounds__(256) void swattn_main(
    const float* __restrict__ x, const float* __restrict__ mask,
    const float* __restrict__ Bp, const float* __restrict__ proj_b,
    const short* __restrict__ mt, const short* __restrict__ wfz,
    const float* __restrict__ uarr, const float* __restrict__ bfu,
    const float* __restrict__ varr, const float* __restrict__ carr,
    float* __restrict__ out)
{
  __shared__ alignas(16) char smem[51200];
  const int tid  = threadIdx.x;
  const int wvid = tid >> 6, lane = tid & 63, lr = lane & 15, lg = lane >> 4;
  const int rbp  = (wvid >> 1) * 2;   // phase-1 row-block pair
  const int jh   = wvid & 1;          // phase-1 j half
  const int wid = blockIdx.x;
  const int bb = wid >> 8, wy = (wid >> 4) & 15, wx = wid & 15;

  // ---- gather shifted window into LDS (LXW, persistent) as bf16 ----
  {
    int token = tid >> 2, q = tid & 3;
    int py = token >> 3, px = token & 7;
    int Y = (wy*8 + py + 4) & 127;
    int X = (wx*8 + px + 4) & 127;
    int swin = bb*256 + ((Y>>3)<<4) + (X>>3);
    int stok = ((Y&7)<<3) + (X&7);
    const float* src = x + ((size_t)(swin*64 + stok))*128 + q*32;
    int base = LXW + token*256 + q*64;
#pragma unroll
    for (int j = 0; j < 32; j += 8) {
      float4 f0 = *(const float4*)(src + j);
      float4 f1 = *(const float4*)(src + j + 4);
      bf16x8 bv;
      bv[0]=f2bf(f0.x); bv[1]=f2bf(f0.y); bv[2]=f2bf(f0.z); bv[3]=f2bf(f0.w);
      bv[4]=f2bf(f1.x); bv[5]=f2bf(f1.y); bv[6]=f2bf(f1.z); bv[7]=f2bf(f1.w);
      *(bf16x8*)(smem + sw256(base + j*2)) = bv;
    }
  }
  __syncthreads();

  // ---- hoist this wave's 2 row-blocks of XW A-fragments (32 VGPR) ----
  // af[r2][kk] = XW[(rbp+r2)*16+lr][kk*64+lg*16 ..] — also P2's kf for
  // cb = rbp, rbp+1 (identical bytes).
  bf16x8 af[2][4];
#pragma unroll
  for (int r2 = 0; r2 < 2; ++r2) {
    int arow = (rbp + r2)*16 + lr;
#pragma unroll
    for (int kk = 0; kk < 4; ++kk)
      af[r2][kk] = *(const bf16x8*)(smem + sw256(LXW + arow*256 + kk*64 + lg*16));
  }

  // ---- rw8[h][i] = v_h . xw_i + c_h  (once per window; pre-scaled) ----
#pragma unroll
  for (int e2 = 0; e2 < 2; ++e2) {
    int e = tid*2 + e2;
    int h = e >> 6, i = e & 63;
    float acc = carr[h];
#pragma unroll
    for (int k8 = 0; k8 < 16; ++k8) {
      bf16x8 xv = lds8(smem, sw256(LXW + i*256 + k8*16));
      float4 va = *(const float4*)(varr + h*128 + k8*8);
      float4 vb = *(const float4*)(varr + h*128 + k8*8 + 4);
      acc += bf2f(xv[0])*va.x + bf2f(xv[1])*va.y + bf2f(xv[2])*va.z + bf2f(xv[3])*va.w;
      acc += bf2f(xv[4])*vb.x + bf2f(xv[5])*vb.y + bf2f(xv[6])*vb.z + bf2f(xv[7])*vb.w;
    }
    *(float*)(smem + LRW + e*4) = acc;
  }
  __syncthreads();   // rw8 visible to all waves

  // ---- border-mask pointer only (values loaded in P2; L1/L2-resident) ----
  const float* mrow = nullptr;
  if (wy == 15 && wx != 15)      mrow = mask;
  else if (wx == 15 && wy != 15) mrow = mask + 4096;
  else if (wy == 15 && wx == 15) mrow = mask + 8192;

  f32x4 accO[8];
#pragma unroll
  for (int ct = 0; ct < 8; ++ct) accO[ct] = f32x4{0.f, 0.f, 0.f, 0.f};

  for (int h = 0; h < 8; ++h) {
    // ===== Phase 1: T = XW.Mt^T (+u) and Vp = XW.Wfz^T (+bfu) ====
    {
      const short* wmat[2] = { mt, wfz };
      const float* bvec[2] = { uarr, bfu };
#pragma unroll
      for (int s = 0; s < 2; ++s) {
#pragma unroll
        for (int t = 0; t < 4; ++t) {
          int j = (jh*4 + t)*16 + lr;
          const short* wr = wmat[s] + (size_t)(h*128 + j)*128;
          bf16x8 bfv[4];
#pragma unroll
          for (int kk = 0; kk < 4; ++kk)
            bfv[kk] = *(const bf16x8*)(wr + kk*32 + lg*8);
          float bias = bvec[s][h*128 + j];
#pragma unroll
          for (int r2 = 0; r2 < 2; ++r2) {
            int rb = rbp + r2;
            f32x4 acc = f32x4{0.f,0.f,0.f,0.f};
#pragma unroll
            for (int kk = 0; kk < 4; ++kk)
              acc = __builtin_amdgcn_mfma_f32_16x16x32_bf16(af[r2][kk], bfv[kk], acc, 0,0,0);
            if (s == 0) {  // T row-major [token][kp], pitch 256B
#pragma unroll
              for (int rr = 0; rr < 4; ++rr) {
                int row = rb*16 + lg*4 + rr;
                *(short*)(smem + sw256(LT + row*256 + j*2)) = f2bf(acc[rr] + bias);
              }
            } else {       // VpT[j][m], pitch 128B, pack 4 m's
              short4 p;
              p.x = f2bf(acc[0] + bias); p.y = f2bf(acc[1] + bias);
              p.z = f2bf(acc[2] + bias); p.w = f2bf(acc[3] + bias);
              int m0 = rb*16 + lg*4;
              *(short4*)(smem + sw128(LV + j*128 + m0*2)) = p;
            }
          }
        }
      }
    }
    __syncthreads();   // bar 1: T/Vp complete

    // ===== Phase 2: att = softmax(T.XW^T + rw + Bp) * wmask  (no max-sub) ====
    // cb loop re-indexed as cb=(rbp+cbx)&3: cbx 0/1 source kf from af (regs),
    // cbx 2/3 from LDS. pv stored in cbx-order (all reg indices compile-time);
    // row ops are order-independent, cb appears only in address math.
    {
      float pv[4][4];  // [cbx][rr]
      bf16x8 qf[4];
      int qrow = 16*wvid + lr;
#pragma unroll
      for (int kk = 0; kk < 4; ++kk)
        qf[kk] = *(const bf16x8*)(smem + sw256(LT + qrow*256 + kk*64 + lg*16));
      int i0 = 16*wvid + lg*4;
      float rwb[4];
#pragma unroll
      for (int rr = 0; rr < 4; ++rr)
        rwb[rr] = *(const float*)(smem + LRW + (h*64 + i0 + rr)*4);
      __builtin_amdgcn_s_setprio(1);
#pragma unroll
      for (int cbx = 0; cbx < 4; ++cbx) {
        int cb = (rbp + cbx) & 3;
        f32x4 at = f32x4{0.f,0.f,0.f,0.f};
        int krow = cb*16 + lr;
#pragma unroll
        for (int kk = 0; kk < 4; ++kk) {
          bf16x8 kf;
          if (cbx == 0)      kf = af[0][kk];
          else if (cbx == 1) kf = af[1][kk];
          else               kf = lds8(smem, sw256(LXW + krow*256 + kk*64 + lg*16));
          at = __builtin_amdgcn_mfma_f32_16x16x32_bf16(qf[kk], kf, at, 0,0,0);
        }
#pragma unroll
        for (int rr = 0; rr < 4; ++rr)
          pv[cbx][rr] = at[rr] + rwb[rr] + Bp[(i0+rr)*64 + cb*16 + lr];
      }
      __builtin_amdgcn_s_setprio(0);
      // scores ~ N(0,1): exp is overflow-safe without max subtraction
#pragma unroll
      for (int rr = 0; rr < 4; ++rr) {
        float s = 0.f;
#pragma unroll
        for (int cbx = 0; cbx < 4; ++cbx) { pv[cbx][rr] = __expf(pv[cbx][rr]); s += pv[cbx][rr]; }
        s += __shfl_xor(s, 1); s += __shfl_xor(s, 2);
        s += __shfl_xor(s, 4); s += __shfl_xor(s, 8);
        float inv = 1.0f / s;
#pragma unroll
        for (int cbx = 0; cbx < 4; ++cbx) pv[cbx][rr] *= inv;
      }
      if (mrow) {
#pragma unroll
        for (int cbx = 0; cbx < 4; ++cbx) {
          int cb = (rbp + cbx) & 3;
#pragma unroll
          for (int rr = 0; rr < 4; ++rr)
            pv[cbx][rr] *= mrow[(i0+rr)*64 + cb*16 + lr];
        }
      }
      // att overlays the wave's OWN LT rows (qf already consumed; bytes 0-127
      // of each row, swizzle stays in-row). In-wave DS ordering, no barrier.
#pragma unroll
      for (int cbx = 0; cbx < 4; ++cbx) {
        int mcol = ((rbp + cbx) & 3)*16 + lr;
#pragma unroll
        for (int rr = 0; rr < 4; ++rr)
          *(short*)(smem + sw256(LT + (i0+rr)*256 + mcol*2)) = f2bf(pv[cbx][rr]);
      }
    }

    // ===== Phase 3: accO[q-slice][all 128 c] += att @ Vp ====
    {
      bf16x8 paf[2];
#pragma unroll
      for (int kk = 0; kk < 2; ++kk)
        paf[kk] = lds8(smem, sw256(LT + (16*wvid + lr)*256 + kk*64 + lg*16));
      __builtin_amdgcn_s_setprio(1);
#pragma unroll
      for (int ct = 0; ct < 8; ++ct) {
        int d = ct*16 + lr;
#pragma unroll
        for (int kk = 0; kk < 2; ++kk) {
          bf16x8 vf = lds8(smem, sw128(LV + d*128 + kk*64 + lg*16));
          accO[ct] = __builtin_amdgcn_mfma_f32_16x16x32_bf16(paf[kk], vf, accO[ct], 0,0,0);
        }
      }
      __builtin_amdgcn_s_setprio(0);
    }
    __syncthreads();   // bar 2: LT/LV reads done before next head's P1
  }

  // ---- epilogue: + proj_b, scatter with reverse shift (own q-slice) ----
#pragma unroll
  for (int rr = 0; rr < 4; ++rr) {
    int i = 16*wvid + lg*4 + rr;
    int py = i >> 3, px = i & 7;
    int Y = (wy*8 + py + 4) & 127;
    int X = (wx*8 + px + 4) & 127;
    int dwin = bb*256 + ((Y>>3)<<4) + (X>>3);
    int dtok = ((Y&7)<<3) + (X&7);
    float* dst = out + ((size_t)(dwin*64 + dtok))*128;
#pragma unroll
    for (int ct = 0; ct < 8; ++ct)
      dst[ct*16 + lr] = accO[ct][rr] + proj_b[ct*16 + lr];
  }
}

extern "C" void kernel_launch(void* const* d_in, const int* in_sizes, int n_in,
                              void* d_out, int out_size, void* d_ws, size_t ws_size,
                              hipStream_t stream) {
  (void)in_sizes; (void)n_in; (void)out_size; (void)ws_size;
  const float* x      = (const float*)d_in[0];
  const float* mask   = (const float*)d_in[1];
  const float* Bp     = (const float*)d_in[2];
  const float* wq_w   = (const float*)d_in[3];
  const float* wq_b   = (const float*)d_in[4];
  const float* wk_w   = (const float*)d_in[5];
  const float* wk_b   = (const float*)d_in[6];
  const float* wv_w   = (const float*)d_in[7];
  const float* wv_b   = (const float*)d_in[8];
  const float* proj_w = (const float*)d_in[9];
  const float* proj_b = (const float*)d_in[10];
  float* out = (float*)d_out;
  short* wsb  = (short*)d_ws;
  short* wfz  = wsb;                       // 131072 shorts
  short* mt   = wsb + 131072;              // 131072 shorts
  float* bfu  = (float*)(wsb + 262144);    // 1024 f
  float* uarr = bfu + 1024;                // 1024 f
  float* varr = bfu + 2048;                // 1024 f
  float* carr = bfu + 3072;                // 8 f

  setup_k<<<2048, 128, 0, stream>>>(proj_w, wv_w, wv_b, wq_w, wk_w, wq_b, wk_b,
                                    wfz, bfu, mt, uarr, varr, carr);
  swattn_main<<<1024, 256, 0, stream>>>(x, mask, Bp, proj_b,
      mt, wfz, uarr, bfu, varr, carr, out);
}

// Round 23
// 164.657 us; speedup vs baseline: 1.5456x; 1.0547x over previous
//
#include <hip/hip_runtime.h>
#include <hip/hip_bf16.h>

typedef __attribute__((ext_vector_type(8))) short bf16x8;
typedef __attribute__((ext_vector_type(4))) float f32x4;

// LDS layout (48 KB): LXW persistent; LT/LV rebuilt per head;
// att overlays the wave's own LT rows (in-wave ordering, certified r15/r17).
// NOTE: the query-side rank-1 terms (x_i·Wq^T·bk + bq·bk) are row-constants
// in the pre-softmax scores and cancel in softmax — not computed at all.
#define LXW  0
#define LT   16384
#define LV   32768

__device__ __forceinline__ int sw256(int o){ return o ^ (((o >> 8) & 7) << 4); }
__device__ __forceinline__ int sw128(int o){ return o ^ (((o >> 7) & 7) << 4); }

// native f32->bf16 RNE conversion
__device__ __forceinline__ short f2bf(float f){
  union { __hip_bfloat16 h; short s; } u;
  u.h = __float2bfloat16(f);
  return u.s;
}
__device__ __forceinline__ bf16x8 lds8(const char* smem, int off){
  return *(const bf16x8*)(smem + off);
}

// Merged setup: blk<1024 -> Wfused role; blk>=1024 -> Mt role (concurrent).
// Wfused_h = pw_h . wv_h (bf16); bfused_h[co] = sum_d wv_b[h*128+d]*pw[co][h*128+d]
// Mt[h][kp][k] = isdk * sum_d Wk[d][kp]*Wq[d][k];
// uarr[h][kp]  = isdk * sum_d bq[d]*Wk[d][kp]   (key-side bias term; survives)
__global__ void setup_k(const float* __restrict__ pw, const float* __restrict__ wv,
                        const float* __restrict__ wv_b,
                        const float* __restrict__ wq, const float* __restrict__ wk,
                        const float* __restrict__ bq,
                        short* __restrict__ wf, float* __restrict__ bf,
                        short* __restrict__ mt, float* __restrict__ uarr) {
  const float isdk = 0.088388347648318447f;  // 1/sqrt(128)
  int blk = blockIdx.x;
  int ci = threadIdx.x;             // 0..127
  if (blk < 1024) {
    int h = blk >> 7, co = blk & 127;
    const float* pr = pw + (size_t)co * 1024 + h * 128;   // pw[co][h*128+d]
    const float* wr = wv + (size_t)h * 128 * 128 + ci;    // wv[h*128+d][ci]
    float acc = 0.f;
#pragma unroll 4
    for (int d = 0; d < 128; ++d)
      acc += pr[d] * wr[(size_t)d * 128];
    wf[(size_t)h * 16384 + co * 128 + ci] = f2bf(acc);
    if (ci < 64) {
      float b = wv_b[h*128 + ci] * pr[ci] + wv_b[h*128 + 64 + ci] * pr[64 + ci];
      b += __shfl_xor(b, 1);  b += __shfl_xor(b, 2);  b += __shfl_xor(b, 4);
      b += __shfl_xor(b, 8);  b += __shfl_xor(b, 16); b += __shfl_xor(b, 32);
      if (ci == 0) bf[h*128 + co] = b;
    }
  } else {
    blk -= 1024;
    int h = blk >> 7, kp = blk & 127;
    const float* wkc = wk + (size_t)h * 16384 + kp;   // Wk[d][kp], stride 128
    const float* wqc = wq + (size_t)h * 16384 + ci;   // Wq[d][k],  stride 128
    float macc = 0.f;
#pragma unroll 4
    for (int d = 0; d < 128; ++d)
      macc += wkc[(size_t)d * 128] * wqc[(size_t)d * 128];
    mt[(size_t)h * 16384 + kp * 128 + ci] = f2bf(macc * isdk);
    if (ci == 0) {
      float u = 0.f;
#pragma unroll 4
      for (int d = 0; d < 128; ++d) u += bq[h*128 + d] * wkc[(size_t)d * 128];
      uarr[h*128 + kp] = u * isdk;
    }
  }
}

__global__ __launch_bounds__(256) void swattn_main(
    const float* __restrict__ x, const float* __restrict__ mask,
    const float* __restrict__ Bp, const float* __restrict__ proj_b,
    const short* __restrict__ mt, const short* __restrict__ wfz,
    const float* __restrict__ uarr, const float* __restrict__ bfu,
    float* __restrict__ out)
{
  __shared__ alignas(16) char smem[49152];
  const int tid  = threadIdx.x;
  const int wvid = tid >> 6, lane = tid & 63, lr = lane & 15, lg = lane >> 4;
  const int rbp  = (wvid >> 1) * 2;   // phase-1 row-block pair
  const int jh   = wvid & 1;          // phase-1 j half
  const int wid = blockIdx.x;
  const int bb = wid >> 8, wy = (wid >> 4) & 15, wx = wid & 15;

  // ---- gather shifted window into LDS (LXW, persistent) as bf16 ----
  {
    int token = tid >> 2, q = tid & 3;
    int py = token >> 3, px = token & 7;
    int Y = (wy*8 + py + 4) & 127;
    int X = (wx*8 + px + 4) & 127;
    int swin = bb*256 + ((Y>>3)<<4) + (X>>3);
    int stok = ((Y&7)<<3) + (X&7);
    const float* src = x + ((size_t)(swin*64 + stok))*128 + q*32;
    int base = LXW + token*256 + q*64;
#pragma unroll
    for (int j = 0; j < 32; j += 8) {
      float4 f0 = *(const float4*)(src + j);
      float4 f1 = *(const float4*)(src + j + 4);
      bf16x8 bv;
      bv[0]=f2bf(f0.x); bv[1]=f2bf(f0.y); bv[2]=f2bf(f0.z); bv[3]=f2bf(f0.w);
      bv[4]=f2bf(f1.x); bv[5]=f2bf(f1.y); bv[6]=f2bf(f1.z); bv[7]=f2bf(f1.w);
      *(bf16x8*)(smem + sw256(base + j*2)) = bv;
    }
  }
  __syncthreads();

  // ---- hoist this wave's 2 row-blocks of XW A-fragments (32 VGPR) ----
  // af[r2][kk] also serves as P2's kf for cb = rbp, rbp+1 (identical bytes).
  bf16x8 af[2][4];
#pragma unroll
  for (int r2 = 0; r2 < 2; ++r2) {
    int arow = (rbp + r2)*16 + lr;
#pragma unroll
    for (int kk = 0; kk < 4; ++kk)
      af[r2][kk] = *(const bf16x8*)(smem + sw256(LXW + arow*256 + kk*64 + lg*16));
  }

  // ---- border-mask pointer only (values loaded in P2; L1/L2-resident) ----
  const float* mrow = nullptr;
  if (wy == 15 && wx != 15)      mrow = mask;
  else if (wx == 15 && wy != 15) mrow = mask + 4096;
  else if (wy == 15 && wx == 15) mrow = mask + 8192;

  f32x4 accO[8];
#pragma unroll
  for (int ct = 0; ct < 8; ++ct) accO[ct] = f32x4{0.f, 0.f, 0.f, 0.f};

  for (int h = 0; h < 8; ++h) {
    // ===== Phase 1: T = XW.Mt^T (+u) and Vp = XW.Wfz^T (+bfu) ====
    {
      const short* wmat[2] = { mt, wfz };
      const float* bvec[2] = { uarr, bfu };
#pragma unroll
      for (int s = 0; s < 2; ++s) {
#pragma unroll
        for (int t = 0; t < 4; ++t) {
          int j = (jh*4 + t)*16 + lr;
          const short* wr = wmat[s] + (size_t)(h*128 + j)*128;
          bf16x8 bfv[4];
#pragma unroll
          for (int kk = 0; kk < 4; ++kk)
            bfv[kk] = *(const bf16x8*)(wr + kk*32 + lg*8);
          float bias = bvec[s][h*128 + j];
#pragma unroll
          for (int r2 = 0; r2 < 2; ++r2) {
            int rb = rbp + r2;
            f32x4 acc = f32x4{0.f,0.f,0.f,0.f};
#pragma unroll
            for (int kk = 0; kk < 4; ++kk)
              acc = __builtin_amdgcn_mfma_f32_16x16x32_bf16(af[r2][kk], bfv[kk], acc, 0,0,0);
            if (s == 0) {  // T row-major [token][kp], pitch 256B
#pragma unroll
              for (int rr = 0; rr < 4; ++rr) {
                int row = rb*16 + lg*4 + rr;
                *(short*)(smem + sw256(LT + row*256 + j*2)) = f2bf(acc[rr] + bias);
              }
            } else {       // VpT[j][m], pitch 128B, pack 4 m's
              short4 p;
              p.x = f2bf(acc[0] + bias); p.y = f2bf(acc[1] + bias);
              p.z = f2bf(acc[2] + bias); p.w = f2bf(acc[3] + bias);
              int m0 = rb*16 + lg*4;
              *(short4*)(smem + sw128(LV + j*128 + m0*2)) = p;
            }
          }
        }
      }
    }
    __syncthreads();   // bar 1: T/Vp complete

    // ===== Phase 2: att = softmax(T.XW^T + Bp) * wmask  (no max-sub) ====
    // cb = (rbp+cbx)&3: cbx 0/1 source kf from af (regs), cbx 2/3 from LDS.
    {
      float pv[4][4];  // [cbx][rr]
      bf16x8 qf[4];
      int qrow = 16*wvid + lr;
#pragma unroll
      for (int kk = 0; kk < 4; ++kk)
        qf[kk] = *(const bf16x8*)(smem + sw256(LT + qrow*256 + kk*64 + lg*16));
      int i0 = 16*wvid + lg*4;
      __builtin_amdgcn_s_setprio(1);
#pragma unroll
      for (int cbx = 0; cbx < 4; ++cbx) {
        int cb = (rbp + cbx) & 3;
        f32x4 at = f32x4{0.f,0.f,0.f,0.f};
        int krow = cb*16 + lr;
#pragma unroll
        for (int kk = 0; kk < 4; ++kk) {
          bf16x8 kf;
          if (cbx == 0)      kf = af[0][kk];
          else if (cbx == 1) kf = af[1][kk];
          else               kf = lds8(smem, sw256(LXW + krow*256 + kk*64 + lg*16));
          at = __builtin_amdgcn_mfma_f32_16x16x32_bf16(qf[kk], kf, at, 0,0,0);
        }
#pragma unroll
        for (int rr = 0; rr < 4; ++rr)
          pv[cbx][rr] = at[rr] + Bp[(i0+rr)*64 + cb*16 + lr];
      }
      __builtin_amdgcn_s_setprio(0);
      // scores ~ N(0,1): exp is overflow-safe without max subtraction
#pragma unroll
      for (int rr = 0; rr < 4; ++rr) {
        float s = 0.f;
#pragma unroll
        for (int cbx = 0; cbx < 4; ++cbx) { pv[cbx][rr] = __expf(pv[cbx][rr]); s += pv[cbx][rr]; }
        s += __shfl_xor(s, 1); s += __shfl_xor(s, 2);
        s += __shfl_xor(s, 4); s += __shfl_xor(s, 8);
        float inv = 1.0f / s;
#pragma unroll
        for (int cbx = 0; cbx < 4; ++cbx) pv[cbx][rr] *= inv;
      }
      if (mrow) {
#pragma unroll
        for (int cbx = 0; cbx < 4; ++cbx) {
          int cb = (rbp + cbx) & 3;
#pragma unroll
          for (int rr = 0; rr < 4; ++rr)
            pv[cbx][rr] *= mrow[(i0+rr)*64 + cb*16 + lr];
        }
      }
      // att overlays the wave's OWN LT rows (qf already consumed; bytes 0-127
      // of each row, swizzle stays in-row). In-wave DS ordering, no barrier.
#pragma unroll
      for (int cbx = 0; cbx < 4; ++cbx) {
        int mcol = ((rbp + cbx) & 3)*16 + lr;
#pragma unroll
        for (int rr = 0; rr < 4; ++rr)
          *(short*)(smem + sw256(LT + (i0+rr)*256 + mcol*2)) = f2bf(pv[cbx][rr]);
      }
    }

    // ===== Phase 3: accO[q-slice][all 128 c] += att @ Vp ====
    {
      bf16x8 paf[2];
#pragma unroll
      for (int kk = 0; kk < 2; ++kk)
        paf[kk] = lds8(smem, sw256(LT + (16*wvid + lr)*256 + kk*64 + lg*16));
      __builtin_amdgcn_s_setprio(1);
#pragma unroll
      for (int ct = 0; ct < 8; ++ct) {
        int d = ct*16 + lr;
#pragma unroll
        for (int kk = 0; kk < 2; ++kk) {
          bf16x8 vf = lds8(smem, sw128(LV + d*128 + kk*64 + lg*16));
          accO[ct] = __builtin_amdgcn_mfma_f32_16x16x32_bf16(paf[kk], vf, accO[ct], 0,0,0);
        }
      }
      __builtin_amdgcn_s_setprio(0);
    }
    __syncthreads();   // bar 2: LT/LV reads done before next head's P1
  }

  // ---- epilogue: + proj_b, scatter with reverse shift (own q-slice) ----
#pragma unroll
  for (int rr = 0; rr < 4; ++rr) {
    int i = 16*wvid + lg*4 + rr;
    int py = i >> 3, px = i & 7;
    int Y = (wy*8 + py + 4) & 127;
    int X = (wx*8 + px + 4) & 127;
    int dwin = bb*256 + ((Y>>3)<<4) + (X>>3);
    int dtok = ((Y&7)<<3) + (X&7);
    float* dst = out + ((size_t)(dwin*64 + dtok))*128;
#pragma unroll
    for (int ct = 0; ct < 8; ++ct)
      dst[ct*16 + lr] = accO[ct][rr] + proj_b[ct*16 + lr];
  }
}

extern "C" void kernel_launch(void* const* d_in, const int* in_sizes, int n_in,
                              void* d_out, int out_size, void* d_ws, size_t ws_size,
                              hipStream_t stream) {
  (void)in_sizes; (void)n_in; (void)out_size; (void)ws_size;
  const float* x      = (const float*)d_in[0];
  const float* mask   = (const float*)d_in[1];
  const float* Bp     = (const float*)d_in[2];
  const float* wq_w   = (const float*)d_in[3];
  const float* wq_b   = (const float*)d_in[4];
  const float* wk_w   = (const float*)d_in[5];
  const float* wk_b   = (const float*)d_in[6];
  const float* wv_w   = (const float*)d_in[7];
  const float* wv_b   = (const float*)d_in[8];
  const float* proj_w = (const float*)d_in[9];
  const float* proj_b = (const float*)d_in[10];
  (void)wk_b;  // key-side bias enters via uarr; query-side terms cancel in softmax
  float* out = (float*)d_out;
  short* wsb  = (short*)d_ws;
  short* wfz  = wsb;                       // 131072 shorts
  short* mt   = wsb + 131072;              // 131072 shorts
  float* bfu  = (float*)(wsb + 262144);    // 1024 f
  float* uarr = bfu + 1024;                // 1024 f

  setup_k<<<2048, 128, 0, stream>>>(proj_w, wv_w, wv_b, wq_w, wk_w, wq_b,
                                    wfz, bfu, mt, uarr);
  swattn_main<<<1024, 256, 0, stream>>>(x, mask, Bp, proj_b,
      mt, wfz, uarr, bfu, out);
}